// Round 6
// baseline (489.649 us; speedup 1.0000x reference)
//
#include <hip/hip_runtime.h>
#include <hip/hip_bf16.h>

// MoE block: N=8192, D=1024, H=1024, E=16, top-k=2. Inputs fp32, output fp32.
// out[n] = w1*(x@W_e1 + b_e1) + w2*(x@W_e2 + b_e2), w = top-2 of softmax.
//
// Round-6:
//  * router: rw staged transposed in LDS (rws[e][d], bank-conflict-free),
//    4 tokens/wave, fp64 accumulation (selection math identical to r4/r5).
//  * fast GEMM path (ws_size >= 56 MB): pre-cast x -> bf16 and W -> bf16
//    TRANSPOSED [e][h][k] in ws; 256x128 tile, BK=32, pure b128 staging
//    (no per-k-iter cvt VALU). Two passes (slot0 write, slot1 RMW) as before.
//  * fallback (small ws): round-5 fp32-staging MFMA kernel (proven).

#define N_TOK 8192
#define D_DIM 1024
#define H_DIM 1024
#define E_NUM 16
#define CAP   1024
#define KPAD  40    // LDS row stride in ushorts (80 B)

typedef __attribute__((ext_vector_type(4))) float f32x4;
typedef __attribute__((ext_vector_type(8))) short bf16x8;

__device__ __forceinline__ unsigned short f2bf(float f) {
    unsigned int u = __float_as_uint(f);
    unsigned int r = u + 0x7fffu + ((u >> 16) & 1u);   // RNE
    return (unsigned short)(r >> 16);
}
__device__ __forceinline__ unsigned int pk2bf(float lo, float hi) {
    return (unsigned int)f2bf(lo) | ((unsigned int)f2bf(hi) << 16);
}

// ---------------- router: 512 blocks x 256 thr, 16 tokens/block ------------
__global__ __launch_bounds__(256) void router_kernel(
    const float* __restrict__ x,
    const float* __restrict__ rw,
    const float* __restrict__ rb,
    int* __restrict__ counts0, int* __restrict__ counts1,
    int2* __restrict__ entries0, int2* __restrict__ entries1)
{
    __shared__ float rws[E_NUM][D_DIM];   // 64 KB, transposed [e][d]

    const int tid = threadIdx.x;
    // stage rw (D x E row-major) -> rws[e][d], coalesced float4 reads
#pragma unroll
    for (int j = 0; j < 16; ++j) {
        const int flat = (j * 256 + tid) * 4;       // 4 consecutive elems
        const float4 v = *(const float4*)(rw + flat);
        const int d = flat >> 4;
        const int e = flat & 15;                    // e, e+1, e+2, e+3
        rws[e + 0][d] = v.x;
        rws[e + 1][d] = v.y;
        rws[e + 2][d] = v.z;
        rws[e + 3][d] = v.w;
    }
    __syncthreads();

    const int wave = tid >> 6;
    const int lane = tid & 63;

    for (int t = 0; t < 4; ++t) {
        const int n = blockIdx.x * 16 + wave * 4 + t;
        const float* xrow = x + (size_t)n * D_DIM;

        double acc[E_NUM];
#pragma unroll
        for (int e = 0; e < E_NUM; ++e) acc[e] = 0.0;

#pragma unroll
        for (int j = 0; j < D_DIM / 64; ++j) {
            const int d = lane + j * 64;
            const double xd = (double)xrow[d];
#pragma unroll
            for (int e = 0; e < E_NUM; ++e)
                acc[e] += xd * (double)rws[e][d];
        }

#pragma unroll
        for (int e = 0; e < E_NUM; ++e) {
            double v = acc[e];
#pragma unroll
            for (int off = 32; off > 0; off >>= 1)
                v += __shfl_xor(v, off);
            acc[e] = v + (double)rb[e];
        }

        if (lane == 0) {
            double m = acc[0];
#pragma unroll
            for (int e = 1; e < E_NUM; ++e) m = fmax(m, acc[e]);
            double p[E_NUM];
            double s = 0.0;
#pragma unroll
            for (int e = 0; e < E_NUM; ++e) { p[e] = exp(acc[e] - m); s += p[e]; }

            int e1 = 0;
#pragma unroll
            for (int e = 1; e < E_NUM; ++e) if (acc[e] > acc[e1]) e1 = e;
            int e2 = (e1 == 0) ? 1 : 0;
            for (int e = 0; e < E_NUM; ++e)
                if (e != e1 && acc[e] > acc[e2]) e2 = e;

            const float w1 = (float)(p[e1] / s);
            const float w2 = (float)(p[e2] / s);

            int pos1 = atomicAdd(&counts0[e1], 1);
            if (pos1 < CAP) entries0[e1 * CAP + pos1] = make_int2(n, __float_as_int(w1));
            int pos2 = atomicAdd(&counts1[e2], 1);
            if (pos2 < CAP) entries1[e2 * CAP + pos2] = make_int2(n, __float_as_int(w2));
        }
    }
}

// ---------------- cast kernels (fast path) ---------------------------------
__global__ __launch_bounds__(256) void cast_x_kernel(
    const float* __restrict__ x, unsigned short* __restrict__ xb)
{
    const size_t i = ((size_t)blockIdx.x * 256 + threadIdx.x) * 8;
    const float4 a = *(const float4*)(x + i);
    const float4 b = *(const float4*)(x + i + 4);
    uint4 o;
    o.x = pk2bf(a.x, a.y); o.y = pk2bf(a.z, a.w);
    o.z = pk2bf(b.x, b.y); o.w = pk2bf(b.z, b.w);
    *(uint4*)(xb + i) = o;
}

// W [e][k][h] fp32 -> w_t [e][h][k] bf16, 64x64 LDS tile transpose
__global__ __launch_bounds__(256) void cast_wt_kernel(
    const float* __restrict__ ew, unsigned short* __restrict__ wt)
{
    __shared__ unsigned short T[64][72];
    const int e  = blockIdx.z;
    const int k0 = blockIdx.y * 64;
    const int h0 = blockIdx.x * 64;
    const int tid = threadIdx.x;

    const int r = tid >> 4;            // 0..15 (+16i)
    const int c = (tid & 15) * 4;
#pragma unroll
    for (int it = 0; it < 4; ++it) {
        const int k = r + it * 16;
        const float4 v = *(const float4*)(ew + ((size_t)(e * 1024 + k0 + k)) * H_DIM + h0 + c);
        ushort4 p;
        p.x = f2bf(v.x); p.y = f2bf(v.y); p.z = f2bf(v.z); p.w = f2bf(v.w);
        *(ushort4*)&T[k][c] = p;
    }
    __syncthreads();

    const int h = tid >> 3;            // 0..31 (+32i)
    const int kc = (tid & 7) * 8;
#pragma unroll
    for (int it = 0; it < 2; ++it) {
        const int hh = h + it * 32;
        uint4 o;
        o.x = (unsigned int)T[kc + 0][hh] | ((unsigned int)T[kc + 1][hh] << 16);
        o.y = (unsigned int)T[kc + 2][hh] | ((unsigned int)T[kc + 3][hh] << 16);
        o.z = (unsigned int)T[kc + 4][hh] | ((unsigned int)T[kc + 5][hh] << 16);
        o.w = (unsigned int)T[kc + 6][hh] | ((unsigned int)T[kc + 7][hh] << 16);
        *(uint4*)(wt + ((size_t)(e * 1024 + h0 + hh)) * D_DIM + k0 + kc) = o;
    }
}

// ---------------- fast GEMM: 256x128 tile, bf16 pre-cast inputs ------------
template <bool ADD>
__global__ __launch_bounds__(256) void gemm_fast_kernel(
    const unsigned short* __restrict__ xb,   // [N][D] bf16
    const unsigned short* __restrict__ wt,   // [E][H][D] bf16 (transposed)
    const float* __restrict__ eb,
    const int* __restrict__ counts,
    const int2* __restrict__ entries,
    float* __restrict__ out)
{
    const int e = blockIdx.z;
    int count = counts[e];
    if (count > CAP) count = CAP;
    const int i0 = blockIdx.y * 256;
    if (i0 >= count) return;
    const int h0 = blockIdx.x * 128;

    __shared__ unsigned short Xs[256][KPAD];   // 20 KB
    __shared__ unsigned short Ws[128][KPAD];   // 10 KB
    __shared__ int   s_tok[256];
    __shared__ float s_w[256];

    const int tid = threadIdx.x;
    {
        const int i = i0 + tid;
        if (i < count) {
            int2 en = entries[e * CAP + i];
            s_tok[tid] = en.x;
            s_w[tid] = __int_as_float(en.y);
        } else {
            s_tok[tid] = 0;
            s_w[tid] = 0.0f;
        }
    }
    __syncthreads();

    const int wave = tid >> 6;
    const int lane = tid & 63;
    const int wr = wave * 64;          // wave's 64-row stripe
    const int l15 = lane & 15;
    const int quad = lane >> 4;

    f32x4 acc[4][8] = {};              // rows 4x16, cols 8x16

    const int a_r = tid >> 2;          // 0..63
    const int a_c = (tid & 3) * 8;     // 16B chunk within 32-k row

    const unsigned short* wbase = wt + ((size_t)e * H_DIM + h0) * D_DIM;

    for (int d0 = 0; d0 < D_DIM; d0 += 32) {
        // A: 256 rows x 32 k (gathered token rows)
#pragma unroll
        for (int it = 0; it < 4; ++it) {
            const int r = a_r + it * 64;
            *(uint4*)&Xs[r][a_c] =
                *(const uint4*)(xb + (size_t)s_tok[r] * D_DIM + d0 + a_c);
        }
        // B: 128 h-rows x 32 k (contiguous, pre-transposed)
#pragma unroll
        for (int it = 0; it < 2; ++it) {
            const int h = a_r + it * 64;
            *(uint4*)&Ws[h][a_c] =
                *(const uint4*)(wbase + (size_t)h * D_DIM + d0 + a_c);
        }
        __syncthreads();

        bf16x8 af[4], bf[8];
#pragma unroll
        for (int i = 0; i < 4; ++i)
            af[i] = *(const bf16x8*)&Xs[wr + i * 16 + l15][quad * 8];
#pragma unroll
        for (int j = 0; j < 8; ++j)
            bf[j] = *(const bf16x8*)&Ws[j * 16 + l15][quad * 8];
#pragma unroll
        for (int i = 0; i < 4; ++i)
#pragma unroll
            for (int j = 0; j < 8; ++j)
                acc[i][j] = __builtin_amdgcn_mfma_f32_16x16x32_bf16(
                    af[i], bf[j], acc[i][j], 0, 0, 0);

        __syncthreads();
    }

    float bias_j[8];
    const float* ebp = eb + e * H_DIM + h0;
#pragma unroll
    for (int j = 0; j < 8; ++j) bias_j[j] = ebp[j * 16 + l15];

#pragma unroll
    for (int i = 0; i < 4; ++i) {
#pragma unroll
        for (int r = 0; r < 4; ++r) {
            const int row = wr + i * 16 + quad * 4 + r;
            if (i0 + row < count) {
                const int tok = s_tok[row];
                const float w = s_w[row];
                float* op = out + (size_t)tok * H_DIM + h0 + l15;
#pragma unroll
                for (int j = 0; j < 8; ++j) {
                    float v = w * (acc[i][j][r] + bias_j[j]);
                    if (ADD) v += op[j * 16];
                    op[j * 16] = v;
                }
            }
        }
    }
}

// ---------------- fallback GEMM (round-5, fp32 staging) --------------------
template <bool ADD>
__global__ __launch_bounds__(256) void moe_mfma_kernel(
    const float* __restrict__ x,
    const float* __restrict__ ew,
    const float* __restrict__ eb,
    const int* __restrict__ counts,
    const int2* __restrict__ entries,
    float* __restrict__ out)
{
    const int e = blockIdx.z;
    int count = counts[e];
    if (count > CAP) count = CAP;
    const int i0 = blockIdx.y * 128;
    if (i0 >= count) return;
    const int h0 = blockIdx.x * 128;

    __shared__ unsigned short Xs[128][KPAD];
    __shared__ unsigned short Ws[128][KPAD];
    __shared__ int   s_tok[128];
    __shared__ float s_w[128];

    const int tid = threadIdx.x;
    if (tid < 128) {
        const int i = i0 + tid;
        if (i < count) {
            int2 en = entries[e * CAP + i];
            s_tok[tid] = en.x;
            s_w[tid] = __int_as_float(en.y);
        } else {
            s_tok[tid] = 0;
            s_w[tid] = 0.0f;
        }
    }
    __syncthreads();

    const int wave = tid >> 6;
    const int lane = tid & 63;
    const int wr = (wave >> 1) * 64;
    const int wc = (wave & 1) * 64;
    const int l15 = lane & 15;
    const int quad = lane >> 4;

    f32x4 acc[4][4] = {};

    const int a_kq = (tid & 7) * 4;
    const int a_r0 = tid >> 3;
    const int b_n  = tid & 127;
    const int b_dh = (tid >> 7) * 16;

    const float* wcol = ew + (size_t)e * D_DIM * H_DIM + h0 + b_n;

    for (int d0 = 0; d0 < D_DIM; d0 += 32) {
#pragma unroll
        for (int it = 0; it < 4; ++it) {
            const int r = a_r0 + it * 32;
            const float4 v = *(const float4*)(x + (size_t)s_tok[r] * D_DIM + d0 + a_kq);
            ushort4 p;
            p.x = f2bf(v.x); p.y = f2bf(v.y); p.z = f2bf(v.z); p.w = f2bf(v.w);
            *(ushort4*)&Xs[r][a_kq] = p;
        }
        {
            float t[16];
#pragma unroll
            for (int i = 0; i < 16; ++i)
                t[i] = wcol[(size_t)(d0 + b_dh + i) * H_DIM];
            uint4 lo, hi;
            lo.x = pk2bf(t[0], t[1]);  lo.y = pk2bf(t[2], t[3]);
            lo.z = pk2bf(t[4], t[5]);  lo.w = pk2bf(t[6], t[7]);
            hi.x = pk2bf(t[8], t[9]);  hi.y = pk2bf(t[10], t[11]);
            hi.z = pk2bf(t[12], t[13]); hi.w = pk2bf(t[14], t[15]);
            *(uint4*)&Ws[b_n][b_dh]     = lo;
            *(uint4*)&Ws[b_n][b_dh + 8] = hi;
        }
        __syncthreads();

        bf16x8 af[4], bq[4];
#pragma unroll
        for (int i = 0; i < 4; ++i)
            af[i] = *(const bf16x8*)&Xs[wr + i * 16 + l15][quad * 8];
#pragma unroll
        for (int j = 0; j < 4; ++j)
            bq[j] = *(const bf16x8*)&Ws[wc + j * 16 + l15][quad * 8];
#pragma unroll
        for (int i = 0; i < 4; ++i)
#pragma unroll
            for (int j = 0; j < 4; ++j)
                acc[i][j] = __builtin_amdgcn_mfma_f32_16x16x32_bf16(
                    af[i], bq[j], acc[i][j], 0, 0, 0);

        __syncthreads();
    }

    float bias_j[4];
    const float* ebp = eb + e * H_DIM + h0 + wc;
#pragma unroll
    for (int j = 0; j < 4; ++j) bias_j[j] = ebp[j * 16 + l15];

#pragma unroll
    for (int i = 0; i < 4; ++i) {
#pragma unroll
        for (int r = 0; r < 4; ++r) {
            const int row = wr + i * 16 + quad * 4 + r;
            if (i0 + row < count) {
                const int tok = s_tok[row];
                const float w = s_w[row];
                float* op = out + (size_t)tok * H_DIM + h0 + wc + l15;
#pragma unroll
                for (int j = 0; j < 4; ++j) {
                    float v = w * (acc[i][j][r] + bias_j[j]);
                    if (ADD) v += op[j * 16];
                    op[j * 16] = v;
                }
            }
        }
    }
}

extern "C" void kernel_launch(void* const* d_in, const int* in_sizes, int n_in,
                              void* d_out, int out_size, void* d_ws, size_t ws_size,
                              hipStream_t stream)
{
    const float* x  = (const float*)d_in[0];
    const float* rw = (const float*)d_in[1];
    const float* rb = (const float*)d_in[2];
    const float* ew = (const float*)d_in[3];
    const float* eb = (const float*)d_in[4];

    char* ws = (char*)d_ws;
    int*  counts0  = (int*)ws;
    int*  counts1  = (int*)(ws + 64);
    int2* entries0 = (int2*)(ws + 1024);
    int2* entries1 = (int2*)(ws + 1024 + E_NUM * CAP * 8);
    unsigned short* xb = (unsigned short*)(ws + (1u << 20));          // 16.78 MB
    unsigned short* wt = (unsigned short*)(ws + (20u << 20));         // 33.55 MB

    const bool fast = ws_size >= (56u << 20);   // host-constant, graph-safe

    hipMemsetAsync(ws, 0, 128, stream);

    router_kernel<<<N_TOK / 16, 256, 0, stream>>>(x, rw, rb, counts0, counts1,
                                                  entries0, entries1);

    if (fast) {
        cast_x_kernel<<<(N_TOK * D_DIM / 8) / 256, 256, 0, stream>>>(x, xb);
        dim3 cg(H_DIM / 64, D_DIM / 64, E_NUM);
        cast_wt_kernel<<<cg, 256, 0, stream>>>(ew, wt);

        dim3 grid(H_DIM / 128, CAP / 256, E_NUM);
        gemm_fast_kernel<false><<<grid, 256, 0, stream>>>(
            xb, wt, eb, counts0, entries0, (float*)d_out);
        gemm_fast_kernel<true><<<grid, 256, 0, stream>>>(
            xb, wt, eb, counts1, entries1, (float*)d_out);
    } else {
        dim3 grid(H_DIM / 128, CAP / 128, E_NUM);
        moe_mfma_kernel<false><<<grid, 256, 0, stream>>>(
            x, ew, eb, counts0, entries0, (float*)d_out);
        moe_mfma_kernel<true><<<grid, 256, 0, stream>>>(
            x, ew, eb, counts1, entries1, (float*)d_out);
    }
}